// Round 3
// baseline (2673.631 us; speedup 1.0000x reference)
//
#include <hip/hip_runtime.h>
#include <stdint.h>

typedef __attribute__((ext_vector_type(8))) short short8;
typedef __attribute__((ext_vector_type(4))) float f32x4;

__device__ __forceinline__ unsigned short f2b(float f) {
  union { float f; uint32_t u; } v; v.f = f;
  uint32_t r = (v.u + 0x7fffu + ((v.u >> 16) & 1u)) >> 16;
  return (unsigned short)r;
}
__device__ __forceinline__ float b2f(unsigned short h) {
  union { uint32_t u; float f; } v; v.u = ((uint32_t)h) << 16; return v.f;
}

__device__ __forceinline__ void load_lds16(const void* g, void* l) {
  __builtin_amdgcn_global_load_lds(
      (const __attribute__((address_space(1))) uint32_t*)g,
      (__attribute__((address_space(3))) uint32_t*)l, 16, 0, 0);
}

// ------------- 256x256 transpose+cast (f32 W[k][n] -> bf16 WT[n][k]) -------------
__global__ void transpose_cast256(const float* __restrict__ W,
                                  unsigned short* __restrict__ WT) {
  __shared__ unsigned short t[32][33];
  int bx = blockIdx.x & 7, by = blockIdx.x >> 3;
  int x = threadIdx.x & 31, y = threadIdx.x >> 5;  // 32x8
  for (int i = 0; i < 32; i += 8)
    t[y + i][x] = f2b(W[(by * 32 + y + i) * 256 + bx * 32 + x]);
  __syncthreads();
  for (int i = 0; i < 32; i += 8)
    WT[(bx * 32 + y + i) * 256 + by * 32 + x] = t[x][y + i];
}

// ------------- GEMM: out[M,256] = A_f32[M,256] @ W + bias_f32 -------------
// A f32 row-major (reg-staged, cast to bf16, swizzled ds_write).
// WT = W^T bf16 row-major (global_load_lds, source pre-swizzled, LDS linear).
// 128x128 tile, BK=64, 4 waves (2x2), 16x16x32 bf16 MFMA.
// Swizzle: physical 16B chunk = logical chunk ^ (row & 7).
template <bool F32OUT>
__global__ __launch_bounds__(256, 2) void gemm_bias(
    const float* __restrict__ A, const unsigned short* __restrict__ WT,
    const float* __restrict__ bias, void* __restrict__ out, int M) {
  __shared__ uint8_t lds[32768];
  uint8_t* ldsA = lds;
  uint8_t* ldsB = lds + 16384;

  const int tid = threadIdx.x;
  const int lane = tid & 63;
  const int w = tid >> 6;
  const int wr = w >> 1, wc = w & 1;
  const int row0 = blockIdx.x * 128;
  const int n0 = blockIdx.y * 128;

  f32x4 acc[4][4] = {};

  for (int kt = 0; kt < 4; ++kt) {
    const int kk = kt << 6;
    // --- stage B: 16KB via global_load_lds, LDS linear, source pre-swizzled ---
#pragma unroll
    for (int c = 0; c < 4; ++c) {
      int q = c * 256 + tid;              // 16B chunk index in LDS
      int row = q >> 3, ch = q & 7;
      int lch = ch ^ (row & 7);           // inverse-swizzled source chunk
      load_lds16(WT + (size_t)(n0 + row) * 256 + kk + lch * 8, ldsB + q * 16);
    }
    // --- stage A: f32 load -> bf16 cvt -> swizzled ds_write_b128 ---
#pragma unroll
    for (int c = 0; c < 4; ++c) {
      int q = c * 256 + tid;
      int row = q >> 3, ch = q & 7;
      int ar = row0 + row;
      if (ar >= M) ar = M - 1;
      const float* ap = A + (size_t)ar * 256 + kk + ch * 8;
      float4 f0 = *(const float4*)(ap);
      float4 f1 = *(const float4*)(ap + 4);
      short8 s;
      s[0] = (short)f2b(f0.x); s[1] = (short)f2b(f0.y);
      s[2] = (short)f2b(f0.z); s[3] = (short)f2b(f0.w);
      s[4] = (short)f2b(f1.x); s[5] = (short)f2b(f1.y);
      s[6] = (short)f2b(f1.z); s[7] = (short)f2b(f1.w);
      *(short8*)(ldsA + row * 128 + ((ch ^ (row & 7)) << 4)) = s;
    }
    asm volatile("s_waitcnt vmcnt(0)" ::: "memory");
    __syncthreads();

#pragma unroll
    for (int s = 0; s < 2; ++s) {
      short8 av[4], bv[4];
      const int cbase = (s << 2) + (lane >> 4);  // logical 16B k-chunk
#pragma unroll
      for (int m = 0; m < 4; ++m) {
        int r = wr * 64 + m * 16 + (lane & 15);
        av[m] = *(const short8*)(ldsA + r * 128 + ((cbase ^ (r & 7)) << 4));
        int cc = wc * 64 + m * 16 + (lane & 15);
        bv[m] = *(const short8*)(ldsB + cc * 128 + ((cbase ^ (cc & 7)) << 4));
      }
#pragma unroll
      for (int m = 0; m < 4; ++m)
#pragma unroll
        for (int n = 0; n < 4; ++n)
          acc[m][n] = __builtin_amdgcn_mfma_f32_16x16x32_bf16(av[m], bv[n],
                                                              acc[m][n], 0, 0, 0);
    }
    __syncthreads();
  }

  // epilogue: + bias, store
#pragma unroll
  for (int n = 0; n < 4; ++n) {
    int col = n0 + wc * 64 + n * 16 + (lane & 15);
    float bval = bias[col];
#pragma unroll
    for (int m = 0; m < 4; ++m) {
#pragma unroll
      for (int j = 0; j < 4; ++j) {
        int row = row0 + wr * 64 + m * 16 + (lane >> 4) * 4 + j;
        if (row < M) {
          float v = acc[m][n][j] + bval;
          if (F32OUT)
            ((float*)out)[(size_t)row * 256 + col] = v;
          else
            ((unsigned short*)out)[(size_t)row * 256 + col] = f2b(v);
        }
      }
    }
  }
}

// ------------- edge scatter: acc[dst] += msg[src] * w -------------
__global__ void edge_scatter(const unsigned short* __restrict__ msg,
                             const int* __restrict__ src, const int* __restrict__ dst,
                             const float* __restrict__ wgt,
                             float* __restrict__ acc, int E) {
  int gw = (blockIdx.x * blockDim.x + threadIdx.x) >> 6;
  int lane = threadIdx.x & 63;
  int nw = (gridDim.x * blockDim.x) >> 6;
  for (int e = gw; e < E; e += nw) {
    int s = src[e], d = dst[e];
    const ushort4 mv = *(const ushort4*)(msg + ((size_t)s << 8) + lane * 4);
    float wt = wgt ? wgt[e] : 1.0f;
    float* ap = acc + ((size_t)d << 8) + lane * 4;
    unsafeAtomicAdd(ap + 0, b2f(mv.x) * wt);
    unsafeAtomicAdd(ap + 1, b2f(mv.y) * wt);
    unsafeAtomicAdd(ap + 2, b2f(mv.z) * wt);
    unsafeAtomicAdd(ap + 3, b2f(mv.w) * wt);
  }
}

// ------------- ELU + f32 store -------------
__global__ void elu_store(const float4* __restrict__ acc, float4* __restrict__ out,
                          int n4) {
  int i0 = blockIdx.x * blockDim.x + threadIdx.x;
  int stride = gridDim.x * blockDim.x;
  for (int i = i0; i < n4; i += stride) {
    float4 v = acc[i];
    float4 o;
    o.x = v.x > 0.f ? v.x : expf(v.x) - 1.f;
    o.y = v.y > 0.f ? v.y : expf(v.y) - 1.f;
    o.z = v.z > 0.f ? v.z : expf(v.z) - 1.f;
    o.w = v.w > 0.f ? v.w : expf(v.w) - 1.f;
    out[i] = o;
  }
}

extern "C" void kernel_launch(void* const* d_in, const int* in_sizes, int n_in,
                              void* d_out, int out_size, void* d_ws, size_t ws_size,
                              hipStream_t stream) {
  const float* x_p = (const float*)d_in[0];
  const float* x_a = (const float*)d_in[1];
  const int* c_src = (const int*)d_in[2];
  const int* c_dst = (const int*)d_in[3];
  const float* c_w = (const float*)d_in[4];
  const int* w_src = (const int*)d_in[5];
  const int* w_dst = (const int*)d_in[6];
  const int* wr_src = (const int*)d_in[7];
  const int* wr_dst = (const int*)d_in[8];
  const float* W_sp = (const float*)d_in[9];
  const float* b_sp = (const float*)d_in[10];
  const float* W_sa = (const float*)d_in[11];
  const float* b_sa = (const float*)d_in[12];
  const float* W_c  = (const float*)d_in[13];
  const float* b_c  = (const float*)d_in[14];
  const float* W_w  = (const float*)d_in[15];
  const float* b_w  = (const float*)d_in[16];
  const float* W_wr = (const float*)d_in[17];
  const float* b_wr = (const float*)d_in[18];

  const int Mp = in_sizes[0] / 256;
  const int Ma = in_sizes[1] / 256;
  const int Ec = in_sizes[2], Ew = in_sizes[5], Ewr = in_sizes[7];

  // workspace layout (~205.5 MB)
  float* acc = (float*)d_ws;                               // (Mp+Ma)*256 f32
  float* acc_p = acc;
  float* acc_a = acc + (size_t)Mp * 256;
  unsigned short* msg = (unsigned short*)(acc + (size_t)(Mp + Ma) * 256);  // Mp*256 bf16
  unsigned short* WT = msg + (size_t)Mp * 256;             // 5 * 65536 bf16
  unsigned short* WT_sp = WT;
  unsigned short* WT_sa = WT + 65536;
  unsigned short* WT_c  = WT + 131072;
  unsigned short* WT_w  = WT + 196608;
  unsigned short* WT_wr = WT + 262144;

  transpose_cast256<<<64, 256, 0, stream>>>(W_sp, WT_sp);
  transpose_cast256<<<64, 256, 0, stream>>>(W_sa, WT_sa);
  transpose_cast256<<<64, 256, 0, stream>>>(W_c,  WT_c);
  transpose_cast256<<<64, 256, 0, stream>>>(W_w,  WT_w);
  transpose_cast256<<<64, 256, 0, stream>>>(W_wr, WT_wr);

  dim3 gp((Mp + 127) / 128, 2), ga((Ma + 127) / 128, 2);

  // self linears -> f32 accumulators
  gemm_bias<true><<<gp, 256, 0, stream>>>(x_p, WT_sp, b_sp, acc_p, Mp);
  gemm_bias<true><<<ga, 256, 0, stream>>>(x_a, WT_sa, b_sa, acc_a, Ma);

  // cites: paper -> paper (weighted)
  gemm_bias<false><<<gp, 256, 0, stream>>>(x_p, WT_c, b_c, msg, Mp);
  edge_scatter<<<2048, 256, 0, stream>>>(msg, c_src, c_dst, c_w, acc_p, Ec);

  // writes: author -> paper
  gemm_bias<false><<<ga, 256, 0, stream>>>(x_a, WT_w, b_w, msg, Ma);
  edge_scatter<<<2048, 256, 0, stream>>>(msg, w_src, w_dst, nullptr, acc_p, Ew);

  // written_by: paper -> author
  gemm_bias<false><<<gp, 256, 0, stream>>>(x_p, WT_wr, b_wr, msg, Mp);
  edge_scatter<<<2048, 256, 0, stream>>>(msg, wr_src, wr_dst, nullptr, acc_a, Ewr);

  // ELU + f32 store, concatenated [out_p ; out_a]
  const int n4 = (Mp + Ma) * 64;
  elu_store<<<2048, 256, 0, stream>>>((const float4*)acc, (float4*)d_out, n4);
}

// Round 4
// 615.743 us; speedup vs baseline: 4.3421x; 4.3421x over previous
//
#include <hip/hip_runtime.h>
#include <stdint.h>

typedef __attribute__((ext_vector_type(8))) short short8;
typedef __attribute__((ext_vector_type(4))) float f32x4;

__device__ __forceinline__ unsigned short f2b(float f) {
  union { float f; uint32_t u; } v; v.f = f;
  uint32_t r = (v.u + 0x7fffu + ((v.u >> 16) & 1u)) >> 16;
  return (unsigned short)r;
}
__device__ __forceinline__ float b2f(unsigned short h) {
  union { uint32_t u; float f; } v; v.u = ((uint32_t)h) << 16; return v.f;
}

__device__ __forceinline__ void load_lds16(const void* g, void* l) {
  __builtin_amdgcn_global_load_lds(
      (const __attribute__((address_space(1))) uint32_t*)g,
      (__attribute__((address_space(3))) uint32_t*)l, 16, 0, 0);
}

// ------------- 256x256 transpose+cast (f32 W[k][n] -> bf16 WT[n][k]) -------------
__global__ void transpose_cast256(const float* __restrict__ W,
                                  unsigned short* __restrict__ WT) {
  __shared__ unsigned short t[32][33];
  int bx = blockIdx.x & 7, by = blockIdx.x >> 3;
  int x = threadIdx.x & 31, y = threadIdx.x >> 5;  // 32x8
  for (int i = 0; i < 32; i += 8)
    t[y + i][x] = f2b(W[(by * 32 + y + i) * 256 + bx * 32 + x]);
  __syncthreads();
  for (int i = 0; i < 32; i += 8)
    WT[(bx * 32 + y + i) * 256 + by * 32 + x] = t[x][y + i];
}

// ------------- GEMM: out[M,256] = A_f32[M,256] @ W + bias_f32 -------------
template <bool F32OUT>
__global__ __launch_bounds__(256, 2) void gemm_bias(
    const float* __restrict__ A, const unsigned short* __restrict__ WT,
    const float* __restrict__ bias, void* __restrict__ out, int M) {
  __shared__ uint8_t lds[32768];
  uint8_t* ldsA = lds;
  uint8_t* ldsB = lds + 16384;

  const int tid = threadIdx.x;
  const int lane = tid & 63;
  const int w = tid >> 6;
  const int wr = w >> 1, wc = w & 1;
  const int row0 = blockIdx.x * 128;
  const int n0 = blockIdx.y * 128;

  f32x4 acc[4][4] = {};

  for (int kt = 0; kt < 4; ++kt) {
    const int kk = kt << 6;
#pragma unroll
    for (int c = 0; c < 4; ++c) {
      int q = c * 256 + tid;              // 16B chunk index in LDS
      int row = q >> 3, ch = q & 7;
      int lch = ch ^ (row & 7);           // inverse-swizzled source chunk
      load_lds16(WT + (size_t)(n0 + row) * 256 + kk + lch * 8, ldsB + q * 16);
    }
#pragma unroll
    for (int c = 0; c < 4; ++c) {
      int q = c * 256 + tid;
      int row = q >> 3, ch = q & 7;
      int ar = row0 + row;
      if (ar >= M) ar = M - 1;
      const float* ap = A + (size_t)ar * 256 + kk + ch * 8;
      float4 f0 = *(const float4*)(ap);
      float4 f1 = *(const float4*)(ap + 4);
      short8 s;
      s[0] = (short)f2b(f0.x); s[1] = (short)f2b(f0.y);
      s[2] = (short)f2b(f0.z); s[3] = (short)f2b(f0.w);
      s[4] = (short)f2b(f1.x); s[5] = (short)f2b(f1.y);
      s[6] = (short)f2b(f1.z); s[7] = (short)f2b(f1.w);
      *(short8*)(ldsA + row * 128 + ((ch ^ (row & 7)) << 4)) = s;
    }
    asm volatile("s_waitcnt vmcnt(0)" ::: "memory");
    __syncthreads();

#pragma unroll
    for (int s = 0; s < 2; ++s) {
      short8 av[4], bv[4];
      const int cbase = (s << 2) + (lane >> 4);
#pragma unroll
      for (int m = 0; m < 4; ++m) {
        int r = wr * 64 + m * 16 + (lane & 15);
        av[m] = *(const short8*)(ldsA + r * 128 + ((cbase ^ (r & 7)) << 4));
        int cc = wc * 64 + m * 16 + (lane & 15);
        bv[m] = *(const short8*)(ldsB + cc * 128 + ((cbase ^ (cc & 7)) << 4));
      }
#pragma unroll
      for (int m = 0; m < 4; ++m)
#pragma unroll
        for (int n = 0; n < 4; ++n)
          acc[m][n] = __builtin_amdgcn_mfma_f32_16x16x32_bf16(av[m], bv[n],
                                                              acc[m][n], 0, 0, 0);
    }
    __syncthreads();
  }

#pragma unroll
  for (int n = 0; n < 4; ++n) {
    int col = n0 + wc * 64 + n * 16 + (lane & 15);
    float bval = bias[col];
#pragma unroll
    for (int m = 0; m < 4; ++m) {
#pragma unroll
      for (int j = 0; j < 4; ++j) {
        int row = row0 + wr * 64 + m * 16 + (lane >> 4) * 4 + j;
        if (row < M) {
          float v = acc[m][n][j] + bval;
          if (F32OUT)
            ((float*)out)[(size_t)row * 256 + col] = v;
          else
            ((unsigned short*)out)[(size_t)row * 256 + col] = f2b(v);
        }
      }
    }
  }
}

// ------------- CSR build -------------
__global__ void hist_kernel(const int* __restrict__ dst, int E, int* __restrict__ cnt) {
  int i = blockIdx.x * blockDim.x + threadIdx.x;
  int stride = gridDim.x * blockDim.x;
  for (; i < E; i += stride) atomicAdd(&cnt[dst[i]], 1);
}

// exclusive scan, chunk of 512 per block (512 threads)
__global__ void scan512(const int* __restrict__ in, int* __restrict__ out,
                        int* __restrict__ bsum, int n) {
  __shared__ int s[512];
  int t = threadIdx.x;
  int i = blockIdx.x * 512 + t;
  int v = (i < n) ? in[i] : 0;
  s[t] = v;
  __syncthreads();
  for (int off = 1; off < 512; off <<= 1) {
    int x = s[t];
    int y = (t >= off) ? s[t - off] : 0;
    __syncthreads();
    s[t] = x + y;
    __syncthreads();
  }
  if (i < n) out[i] = s[t] - v;  // exclusive
  if (t == 511) bsum[blockIdx.x] = s[511];
}

__global__ void scan_bsums(int* __restrict__ bsum, int B) {  // 1 block, 512 thr
  __shared__ int s[512];
  int t = threadIdx.x;
  int v = (t < B) ? bsum[t] : 0;
  s[t] = v;
  __syncthreads();
  for (int off = 1; off < 512; off <<= 1) {
    int x = s[t];
    int y = (t >= off) ? s[t - off] : 0;
    __syncthreads();
    s[t] = x + y;
    __syncthreads();
  }
  if (t < B) bsum[t] = s[t] - v;  // exclusive
}

__global__ void scan_addoff(int* __restrict__ out, const int* __restrict__ bsum, int n) {
  int i = blockIdx.x * 512 + threadIdx.x;
  if (i < n) out[i] += bsum[blockIdx.x];
}

__global__ void bucket_kernel(const int* __restrict__ dst, int E,
                              int* __restrict__ pos, int* __restrict__ perm) {
  int i = blockIdx.x * blockDim.x + threadIdx.x;
  int stride = gridDim.x * blockDim.x;
  for (; i < E; i += stride) {
    int s = atomicAdd(&pos[dst[i]], 1);
    perm[s] = i;
  }
}

// ------------- fused gather-accumulate + ELU (1 wave per dst row) -------------
__global__ void accum_relations(
    float* __restrict__ io, int N,
    const unsigned short* __restrict__ msg1, const int* __restrict__ off1,
    const int* __restrict__ perm1, const int* __restrict__ src1,
    const float* __restrict__ wgt1,
    const unsigned short* __restrict__ msg2, const int* __restrict__ off2,
    const int* __restrict__ perm2, const int* __restrict__ src2) {
  int gw = (blockIdx.x * blockDim.x + threadIdx.x) >> 6;
  int lane = threadIdx.x & 63;
  if (gw >= N) return;
  float* rp = io + (size_t)gw * 256 + lane * 4;
  float4 v = *(float4*)rp;
  int b0 = off1[gw], e0 = off1[gw + 1];
  for (int j = b0; j < e0; ++j) {
    int e = perm1[j];
    int s = src1[e];
    float w = wgt1 ? wgt1[e] : 1.0f;
    ushort4 m = *(const ushort4*)(msg1 + ((size_t)s << 8) + lane * 4);
    v.x += w * b2f(m.x); v.y += w * b2f(m.y);
    v.z += w * b2f(m.z); v.w += w * b2f(m.w);
  }
  if (msg2) {
    int b1 = off2[gw], e1 = off2[gw + 1];
    for (int j = b1; j < e1; ++j) {
      int e = perm2[j];
      int s = src2[e];
      ushort4 m = *(const ushort4*)(msg2 + ((size_t)s << 8) + lane * 4);
      v.x += b2f(m.x); v.y += b2f(m.y); v.z += b2f(m.z); v.w += b2f(m.w);
    }
  }
  v.x = v.x > 0.f ? v.x : expf(v.x) - 1.f;
  v.y = v.y > 0.f ? v.y : expf(v.y) - 1.f;
  v.z = v.z > 0.f ? v.z : expf(v.z) - 1.f;
  v.w = v.w > 0.f ? v.w : expf(v.w) - 1.f;
  *(float4*)rp = v;
}

extern "C" void kernel_launch(void* const* d_in, const int* in_sizes, int n_in,
                              void* d_out, int out_size, void* d_ws, size_t ws_size,
                              hipStream_t stream) {
  const float* x_p = (const float*)d_in[0];
  const float* x_a = (const float*)d_in[1];
  const int* c_src = (const int*)d_in[2];
  const int* c_dst = (const int*)d_in[3];
  const float* c_w = (const float*)d_in[4];
  const int* w_src = (const int*)d_in[5];
  const int* w_dst = (const int*)d_in[6];
  const int* wr_src = (const int*)d_in[7];
  const int* wr_dst = (const int*)d_in[8];
  const float* W_sp = (const float*)d_in[9];
  const float* b_sp = (const float*)d_in[10];
  const float* W_sa = (const float*)d_in[11];
  const float* b_sa = (const float*)d_in[12];
  const float* W_c  = (const float*)d_in[13];
  const float* b_c  = (const float*)d_in[14];
  const float* W_w  = (const float*)d_in[15];
  const float* b_w  = (const float*)d_in[16];
  const float* W_wr = (const float*)d_in[17];
  const float* b_wr = (const float*)d_in[18];

  const int Mp = in_sizes[0] / 256;
  const int Ma = in_sizes[1] / 256;
  const int Ec = in_sizes[2], Ew = in_sizes[5], Ewr = in_sizes[7];

  // ---- workspace bump allocator (256B aligned) ----
  size_t wo = 0;
  auto alloc = [&](size_t bytes) -> void* {
    void* p = (char*)d_ws + wo;
    wo += (bytes + 255) & ~(size_t)255;
    return p;
  };
  unsigned short* msg_c  = (unsigned short*)alloc((size_t)Mp * 512);
  unsigned short* msg_w  = (unsigned short*)alloc((size_t)Ma * 512);
  unsigned short* msg_wr = (unsigned short*)alloc((size_t)Mp * 512);
  unsigned short* WT_sp = (unsigned short*)alloc(131072);
  unsigned short* WT_sa = (unsigned short*)alloc(131072);
  unsigned short* WT_c  = (unsigned short*)alloc(131072);
  unsigned short* WT_w  = (unsigned short*)alloc(131072);
  unsigned short* WT_wr = (unsigned short*)alloc(131072);
  int* cnt_c  = (int*)alloc((size_t)(Mp + 1) * 4);
  int* off_c  = (int*)alloc((size_t)(Mp + 1) * 4);
  int* pos_c  = (int*)alloc((size_t)Mp * 4);
  int* perm_c = (int*)alloc((size_t)Ec * 4);
  int* cnt_w  = (int*)alloc((size_t)(Mp + 1) * 4);
  int* off_w  = (int*)alloc((size_t)(Mp + 1) * 4);
  int* pos_w  = (int*)alloc((size_t)Mp * 4);
  int* perm_w = (int*)alloc((size_t)Ew * 4);
  int* cnt_wr  = (int*)alloc((size_t)(Ma + 1) * 4);
  int* off_wr  = (int*)alloc((size_t)(Ma + 1) * 4);
  int* pos_wr  = (int*)alloc((size_t)Ma * 4);
  int* perm_wr = (int*)alloc((size_t)Ewr * 4);
  int* bsum = (int*)alloc(512 * 4);

  float* out_p = (float*)d_out;
  float* out_a = (float*)d_out + (size_t)Mp * 256;

  // ---- weight transposes ----
  transpose_cast256<<<64, 256, 0, stream>>>(W_sp, WT_sp);
  transpose_cast256<<<64, 256, 0, stream>>>(W_sa, WT_sa);
  transpose_cast256<<<64, 256, 0, stream>>>(W_c,  WT_c);
  transpose_cast256<<<64, 256, 0, stream>>>(W_w,  WT_w);
  transpose_cast256<<<64, 256, 0, stream>>>(W_wr, WT_wr);

  // ---- CSR build for the three relations ----
  struct Rel { const int* dst; int E; int n; int* cnt; int* off; int* pos; int* perm; };
  Rel rels[3] = {
    {c_dst,  Ec,  Mp, cnt_c,  off_c,  pos_c,  perm_c},
    {w_dst,  Ew,  Mp, cnt_w,  off_w,  pos_w,  perm_w},
    {wr_dst, Ewr, Ma, cnt_wr, off_wr, pos_wr, perm_wr},
  };
  for (int r = 0; r < 3; ++r) {
    Rel& R = rels[r];
    int ns = R.n + 1;
    int Ba = (ns + 511) / 512;
    hipMemsetAsync(R.cnt, 0, (size_t)ns * 4, stream);
    hist_kernel<<<256, 256, 0, stream>>>(R.dst, R.E, R.cnt);
    scan512<<<Ba, 512, 0, stream>>>(R.cnt, R.off, bsum, ns);
    scan_bsums<<<1, 512, 0, stream>>>(bsum, Ba);
    scan_addoff<<<Ba, 512, 0, stream>>>(R.off, bsum, ns);
    hipMemcpyAsync(R.pos, R.off, (size_t)R.n * 4, hipMemcpyDeviceToDevice, stream);
    bucket_kernel<<<256, 256, 0, stream>>>(R.dst, R.E, R.pos, R.perm);
  }

  // ---- GEMMs: self -> d_out (f32), messages -> bf16 buffers ----
  dim3 gp((Mp + 127) / 128, 2), ga((Ma + 127) / 128, 2);
  gemm_bias<true><<<gp, 256, 0, stream>>>(x_p, WT_sp, b_sp, out_p, Mp);
  gemm_bias<true><<<ga, 256, 0, stream>>>(x_a, WT_sa, b_sa, out_a, Ma);
  gemm_bias<false><<<gp, 256, 0, stream>>>(x_p, WT_c,  b_c,  msg_c,  Mp);
  gemm_bias<false><<<ga, 256, 0, stream>>>(x_a, WT_w,  b_w,  msg_w,  Ma);
  gemm_bias<false><<<gp, 256, 0, stream>>>(x_p, WT_wr, b_wr, msg_wr, Mp);

  // ---- fused gather-accumulate + ELU ----
  accum_relations<<<(Mp + 3) / 4, 256, 0, stream>>>(
      out_p, Mp, msg_c, off_c, perm_c, c_src, c_w,
      msg_w, off_w, perm_w, w_src);
  accum_relations<<<(Ma + 3) / 4, 256, 0, stream>>>(
      out_a, Ma, msg_wr, off_wr, perm_wr, wr_src, nullptr,
      nullptr, nullptr, nullptr, nullptr);
}

// Round 5
// 501.021 us; speedup vs baseline: 5.3364x; 1.2290x over previous
//
#include <hip/hip_runtime.h>
#include <stdint.h>

typedef __attribute__((ext_vector_type(8))) short short8;
typedef __attribute__((ext_vector_type(4))) float f32x4;

__device__ __forceinline__ unsigned short f2b(float f) {
  union { float f; uint32_t u; } v; v.f = f;
  uint32_t r = (v.u + 0x7fffu + ((v.u >> 16) & 1u)) >> 16;
  return (unsigned short)r;
}
__device__ __forceinline__ float b2f(unsigned short h) {
  union { uint32_t u; float f; } v; v.u = ((uint32_t)h) << 16; return v.f;
}

__device__ __forceinline__ void load_lds16(const void* g, void* l) {
  __builtin_amdgcn_global_load_lds(
      (const __attribute__((address_space(1))) uint32_t*)g,
      (__attribute__((address_space(3))) uint32_t*)l, 16, 0, 0);
}

// ------------- 5x fused 256x256 transpose+cast (f32 W[k][n] -> bf16 WT[n][k]) -------------
__global__ void transpose_cast5(
    const float* __restrict__ W0, const float* __restrict__ W1,
    const float* __restrict__ W2, const float* __restrict__ W3,
    const float* __restrict__ W4,
    unsigned short* __restrict__ T0, unsigned short* __restrict__ T1,
    unsigned short* __restrict__ T2, unsigned short* __restrict__ T3,
    unsigned short* __restrict__ T4) {
  const float* W; unsigned short* T;
  switch (blockIdx.y) {
    case 0: W = W0; T = T0; break;
    case 1: W = W1; T = T1; break;
    case 2: W = W2; T = T2; break;
    case 3: W = W3; T = T3; break;
    default: W = W4; T = T4; break;
  }
  __shared__ unsigned short t[32][33];
  int bx = blockIdx.x & 7, by = blockIdx.x >> 3;
  int x = threadIdx.x & 31, y = threadIdx.x >> 5;  // 32x8
  for (int i = 0; i < 32; i += 8)
    t[y + i][x] = f2b(W[(by * 32 + y + i) * 256 + bx * 32 + x]);
  __syncthreads();
  for (int i = 0; i < 32; i += 8)
    T[(bx * 32 + y + i) * 256 + by * 32 + x] = t[x][y + i];
}

// ------------- GEMM: out[M,256] = A_f32[M,256] @ W + bias_f32 -------------
template <bool F32OUT>
__global__ __launch_bounds__(256, 2) void gemm_bias(
    const float* __restrict__ A, const unsigned short* __restrict__ WT,
    const float* __restrict__ bias, void* __restrict__ out, int M) {
  __shared__ uint8_t lds[32768];
  uint8_t* ldsA = lds;
  uint8_t* ldsB = lds + 16384;

  const int tid = threadIdx.x;
  const int lane = tid & 63;
  const int w = tid >> 6;
  const int wr = w >> 1, wc = w & 1;
  const int row0 = blockIdx.x * 128;
  const int n0 = blockIdx.y * 128;

  f32x4 acc[4][4] = {};

  for (int kt = 0; kt < 4; ++kt) {
    const int kk = kt << 6;
#pragma unroll
    for (int c = 0; c < 4; ++c) {
      int q = c * 256 + tid;              // 16B chunk index in LDS
      int row = q >> 3, ch = q & 7;
      int lch = ch ^ (row & 7);           // inverse-swizzled source chunk
      load_lds16(WT + (size_t)(n0 + row) * 256 + kk + lch * 8, ldsB + q * 16);
    }
#pragma unroll
    for (int c = 0; c < 4; ++c) {
      int q = c * 256 + tid;
      int row = q >> 3, ch = q & 7;
      int ar = row0 + row;
      if (ar >= M) ar = M - 1;
      const float* ap = A + (size_t)ar * 256 + kk + ch * 8;
      float4 f0 = *(const float4*)(ap);
      float4 f1 = *(const float4*)(ap + 4);
      short8 s;
      s[0] = (short)f2b(f0.x); s[1] = (short)f2b(f0.y);
      s[2] = (short)f2b(f0.z); s[3] = (short)f2b(f0.w);
      s[4] = (short)f2b(f1.x); s[5] = (short)f2b(f1.y);
      s[6] = (short)f2b(f1.z); s[7] = (short)f2b(f1.w);
      *(short8*)(ldsA + row * 128 + ((ch ^ (row & 7)) << 4)) = s;
    }
    asm volatile("s_waitcnt vmcnt(0)" ::: "memory");
    __syncthreads();

#pragma unroll
    for (int s = 0; s < 2; ++s) {
      short8 av[4], bv[4];
      const int cbase = (s << 2) + (lane >> 4);
#pragma unroll
      for (int m = 0; m < 4; ++m) {
        int r = wr * 64 + m * 16 + (lane & 15);
        av[m] = *(const short8*)(ldsA + r * 128 + ((cbase ^ (r & 7)) << 4));
        int cc = wc * 64 + m * 16 + (lane & 15);
        bv[m] = *(const short8*)(ldsB + cc * 128 + ((cbase ^ (cc & 7)) << 4));
      }
#pragma unroll
      for (int m = 0; m < 4; ++m)
#pragma unroll
        for (int n = 0; n < 4; ++n)
          acc[m][n] = __builtin_amdgcn_mfma_f32_16x16x32_bf16(av[m], bv[n],
                                                              acc[m][n], 0, 0, 0);
    }
    __syncthreads();
  }

#pragma unroll
  for (int n = 0; n < 4; ++n) {
    int col = n0 + wc * 64 + n * 16 + (lane & 15);
    float bval = bias[col];
#pragma unroll
    for (int m = 0; m < 4; ++m) {
#pragma unroll
      for (int j = 0; j < 4; ++j) {
        int row = row0 + wr * 64 + m * 16 + (lane >> 4) * 4 + j;
        if (row < M) {
          float v = acc[m][n][j] + bval;
          if (F32OUT)
            ((float*)out)[(size_t)row * 256 + col] = v;
          else
            ((unsigned short*)out)[(size_t)row * 256 + col] = f2b(v);
        }
      }
    }
  }
}

// ------------- CSR build (fused over 3 relations) -------------
__global__ void hist3(const int* __restrict__ d1, int E1, int* __restrict__ c1,
                      const int* __restrict__ d2, int E2, int* __restrict__ c2,
                      const int* __restrict__ d3, int E3, int* __restrict__ c3) {
  int i = blockIdx.x * blockDim.x + threadIdx.x;
  int stride = gridDim.x * blockDim.x;
  int tot = E1 + E2 + E3;
  for (; i < tot; i += stride) {
    if (i < E1) atomicAdd(&c1[d1[i]], 1);
    else if (i < E1 + E2) atomicAdd(&c2[d2[i - E1]], 1);
    else atomicAdd(&c3[d3[i - E1 - E2]], 1);
  }
}

// batched exclusive scans: blockIdx.y = relation
__global__ void scan512_3(const int* __restrict__ c1, int* __restrict__ o1, int ns1,
                          const int* __restrict__ c2, int* __restrict__ o2, int ns2,
                          const int* __restrict__ c3, int* __restrict__ o3, int ns3,
                          int* __restrict__ bsum) {
  const int* in; int* out; int ns;
  switch (blockIdx.y) {
    case 0: in = c1; out = o1; ns = ns1; break;
    case 1: in = c2; out = o2; ns = ns2; break;
    default: in = c3; out = o3; ns = ns3; break;
  }
  if ((int)blockIdx.x * 512 >= ns) return;
  __shared__ int s[512];
  int t = threadIdx.x;
  int i = blockIdx.x * 512 + t;
  int v = (i < ns) ? in[i] : 0;
  s[t] = v;
  __syncthreads();
  for (int off = 1; off < 512; off <<= 1) {
    int x = s[t];
    int y = (t >= off) ? s[t - off] : 0;
    __syncthreads();
    s[t] = x + y;
    __syncthreads();
  }
  if (i < ns) out[i] = s[t] - v;  // exclusive
  if (t == 511) bsum[blockIdx.y * 512 + blockIdx.x] = s[511];
}

__global__ void scan_bsums3(int* __restrict__ bsum, int B1, int B2, int B3) {
  int rel = blockIdx.x;
  int B = rel == 0 ? B1 : (rel == 1 ? B2 : B3);
  int* bs = bsum + rel * 512;
  __shared__ int s[512];
  int t = threadIdx.x;
  int v = (t < B) ? bs[t] : 0;
  s[t] = v;
  __syncthreads();
  for (int off = 1; off < 512; off <<= 1) {
    int x = s[t];
    int y = (t >= off) ? s[t - off] : 0;
    __syncthreads();
    s[t] = x + y;
    __syncthreads();
  }
  if (t < B) bs[t] = s[t] - v;  // exclusive
}

// add block offsets; also seed pos[] = final exclusive offsets
__global__ void addoff3(int* __restrict__ o1, int* __restrict__ p1, int ns1,
                        int* __restrict__ o2, int* __restrict__ p2, int ns2,
                        int* __restrict__ o3, int* __restrict__ p3, int ns3,
                        const int* __restrict__ bsum) {
  int* o; int* p; int ns;
  switch (blockIdx.y) {
    case 0: o = o1; p = p1; ns = ns1; break;
    case 1: o = o2; p = p2; ns = ns2; break;
    default: o = o3; p = p3; ns = ns3; break;
  }
  int i = blockIdx.x * 512 + threadIdx.x;
  if (i < ns) {
    int v = o[i] + bsum[blockIdx.y * 512 + blockIdx.x];
    o[i] = v;
    p[i] = v;
  }
}

// bucket: write permuted src (and weight for rel1) directly
__global__ void bucket3(
    const int* __restrict__ d1, const int* __restrict__ s1in,
    const float* __restrict__ w1in, int E1, int* __restrict__ p1,
    int* __restrict__ s1, float* __restrict__ w1,
    const int* __restrict__ d2, const int* __restrict__ s2in, int E2,
    int* __restrict__ p2, int* __restrict__ s2,
    const int* __restrict__ d3, const int* __restrict__ s3in, int E3,
    int* __restrict__ p3, int* __restrict__ s3) {
  int i = blockIdx.x * blockDim.x + threadIdx.x;
  int stride = gridDim.x * blockDim.x;
  int tot = E1 + E2 + E3;
  for (; i < tot; i += stride) {
    if (i < E1) {
      int p = atomicAdd(&p1[d1[i]], 1);
      s1[p] = s1in[i];
      w1[p] = w1in[i];
    } else if (i < E1 + E2) {
      int k = i - E1;
      int p = atomicAdd(&p2[d2[k]], 1);
      s2[p] = s2in[k];
    } else {
      int k = i - E1 - E2;
      int p = atomicAdd(&p3[d3[k]], 1);
      s3[p] = s3in[k];
    }
  }
}

// ------------- fused gather-accumulate + ELU (1 wave per dst row) -------------
template <bool WEIGHTED>
__device__ __forceinline__ void gather_acc(float4& v, const unsigned short* __restrict__ msg,
                                           const int* __restrict__ srcs,
                                           const float* __restrict__ wgts,
                                           int b, int e, int lane) {
  int j = b;
  for (; j + 4 <= e; j += 4) {
    int sa = srcs[j], sb = srcs[j + 1], sc = srcs[j + 2], sd = srcs[j + 3];
    float wa = 1.f, wb = 1.f, wc = 1.f, wd = 1.f;
    if (WEIGHTED) { wa = wgts[j]; wb = wgts[j + 1]; wc = wgts[j + 2]; wd = wgts[j + 3]; }
    ushort4 ma = *(const ushort4*)(msg + ((size_t)sa << 8) + lane * 4);
    ushort4 mb = *(const ushort4*)(msg + ((size_t)sb << 8) + lane * 4);
    ushort4 mc = *(const ushort4*)(msg + ((size_t)sc << 8) + lane * 4);
    ushort4 md = *(const ushort4*)(msg + ((size_t)sd << 8) + lane * 4);
    v.x += wa * b2f(ma.x) + wb * b2f(mb.x) + wc * b2f(mc.x) + wd * b2f(md.x);
    v.y += wa * b2f(ma.y) + wb * b2f(mb.y) + wc * b2f(mc.y) + wd * b2f(md.y);
    v.z += wa * b2f(ma.z) + wb * b2f(mb.z) + wc * b2f(mc.z) + wd * b2f(md.z);
    v.w += wa * b2f(ma.w) + wb * b2f(mb.w) + wc * b2f(mc.w) + wd * b2f(md.w);
  }
  for (; j < e; ++j) {
    int s = srcs[j];
    float w = WEIGHTED ? wgts[j] : 1.f;
    ushort4 m = *(const ushort4*)(msg + ((size_t)s << 8) + lane * 4);
    v.x += w * b2f(m.x); v.y += w * b2f(m.y);
    v.z += w * b2f(m.z); v.w += w * b2f(m.w);
  }
}

__global__ void accum_fused(
    float* __restrict__ io_p, int Np, float* __restrict__ io_a, int Na,
    const unsigned short* __restrict__ msg1, const int* __restrict__ off1,
    const int* __restrict__ s1, const float* __restrict__ w1,
    const unsigned short* __restrict__ msg2, const int* __restrict__ off2,
    const int* __restrict__ s2,
    const unsigned short* __restrict__ msg3, const int* __restrict__ off3,
    const int* __restrict__ s3) {
  int gw = (blockIdx.x * blockDim.x + threadIdx.x) >> 6;
  int lane = threadIdx.x & 63;
  float* rp;
  float4 v;
  if (gw < Np) {
    rp = io_p + (size_t)gw * 256 + lane * 4;
    v = *(float4*)rp;
    gather_acc<true>(v, msg1, s1, w1, off1[gw], off1[gw + 1], lane);
    gather_acc<false>(v, msg2, s2, nullptr, off2[gw], off2[gw + 1], lane);
  } else if (gw < Np + Na) {
    int r = gw - Np;
    rp = io_a + (size_t)r * 256 + lane * 4;
    v = *(float4*)rp;
    gather_acc<false>(v, msg3, s3, nullptr, off3[r], off3[r + 1], lane);
  } else {
    return;
  }
  v.x = v.x > 0.f ? v.x : expf(v.x) - 1.f;
  v.y = v.y > 0.f ? v.y : expf(v.y) - 1.f;
  v.z = v.z > 0.f ? v.z : expf(v.z) - 1.f;
  v.w = v.w > 0.f ? v.w : expf(v.w) - 1.f;
  *(float4*)rp = v;
}

extern "C" void kernel_launch(void* const* d_in, const int* in_sizes, int n_in,
                              void* d_out, int out_size, void* d_ws, size_t ws_size,
                              hipStream_t stream) {
  const float* x_p = (const float*)d_in[0];
  const float* x_a = (const float*)d_in[1];
  const int* c_src = (const int*)d_in[2];
  const int* c_dst = (const int*)d_in[3];
  const float* c_w = (const float*)d_in[4];
  const int* w_src = (const int*)d_in[5];
  const int* w_dst = (const int*)d_in[6];
  const int* wr_src = (const int*)d_in[7];
  const int* wr_dst = (const int*)d_in[8];
  const float* W_sp = (const float*)d_in[9];
  const float* b_sp = (const float*)d_in[10];
  const float* W_sa = (const float*)d_in[11];
  const float* b_sa = (const float*)d_in[12];
  const float* W_c  = (const float*)d_in[13];
  const float* b_c  = (const float*)d_in[14];
  const float* W_w  = (const float*)d_in[15];
  const float* b_w  = (const float*)d_in[16];
  const float* W_wr = (const float*)d_in[17];
  const float* b_wr = (const float*)d_in[18];

  const int Mp = in_sizes[0] / 256;
  const int Ma = in_sizes[1] / 256;
  const int Ec = in_sizes[2], Ew = in_sizes[5], Ewr = in_sizes[7];

  // ---- workspace bump allocator (256B aligned) ----
  size_t wo = 0;
  auto alloc = [&](size_t bytes) -> void* {
    void* p = (char*)d_ws + wo;
    wo += (bytes + 255) & ~(size_t)255;
    return p;
  };
  unsigned short* msg_c  = (unsigned short*)alloc((size_t)Mp * 512);
  unsigned short* msg_w  = (unsigned short*)alloc((size_t)Ma * 512);
  unsigned short* msg_wr = (unsigned short*)alloc((size_t)Mp * 512);
  unsigned short* WT_sp = (unsigned short*)alloc(131072);
  unsigned short* WT_sa = (unsigned short*)alloc(131072);
  unsigned short* WT_c  = (unsigned short*)alloc(131072);
  unsigned short* WT_w  = (unsigned short*)alloc(131072);
  unsigned short* WT_wr = (unsigned short*)alloc(131072);
  // contiguous cnt arrays (single memset)
  int* cnt_c  = (int*)alloc((size_t)(Mp + 1) * 4 + (size_t)(Mp + 1) * 4 + (size_t)(Ma + 1) * 4);
  int* cnt_w  = cnt_c + (Mp + 1);
  int* cnt_wr = cnt_w + (Mp + 1);
  size_t cnt_bytes = (size_t)((Mp + 1) + (Mp + 1) + (Ma + 1)) * 4;
  int* off_c  = (int*)alloc((size_t)(Mp + 1) * 4);
  int* pos_c  = (int*)alloc((size_t)(Mp + 1) * 4);
  int* off_w  = (int*)alloc((size_t)(Mp + 1) * 4);
  int* pos_w  = (int*)alloc((size_t)(Mp + 1) * 4);
  int* off_wr = (int*)alloc((size_t)(Ma + 1) * 4);
  int* pos_wr = (int*)alloc((size_t)(Ma + 1) * 4);
  int* srcs_c  = (int*)alloc((size_t)Ec * 4);
  float* wgts_c = (float*)alloc((size_t)Ec * 4);
  int* srcs_w  = (int*)alloc((size_t)Ew * 4);
  int* srcs_wr = (int*)alloc((size_t)Ewr * 4);
  int* bsum = (int*)alloc(3 * 512 * 4);

  float* out_p = (float*)d_out;
  float* out_a = (float*)d_out + (size_t)Mp * 256;

  // ---- weight transposes (1 dispatch) ----
  {
    dim3 g(64, 5);
    transpose_cast5<<<g, 256, 0, stream>>>(W_sp, W_sa, W_c, W_w, W_wr,
                                           WT_sp, WT_sa, WT_c, WT_w, WT_wr);
  }

  // ---- CSR build (6 dispatches total) ----
  const int ns1 = Mp + 1, ns2 = Mp + 1, ns3 = Ma + 1;
  const int B1 = (ns1 + 511) / 512, B2 = (ns2 + 511) / 512, B3 = (ns3 + 511) / 512;
  const int Bmax = B1 > B2 ? (B1 > B3 ? B1 : B3) : (B2 > B3 ? B2 : B3);
  hipMemsetAsync(cnt_c, 0, cnt_bytes, stream);
  hist3<<<256, 256, 0, stream>>>(c_dst, Ec, cnt_c, w_dst, Ew, cnt_w, wr_dst, Ewr, cnt_wr);
  {
    dim3 g(Bmax, 3);
    scan512_3<<<g, 512, 0, stream>>>(cnt_c, off_c, ns1, cnt_w, off_w, ns2,
                                     cnt_wr, off_wr, ns3, bsum);
    scan_bsums3<<<3, 512, 0, stream>>>(bsum, B1, B2, B3);
    addoff3<<<g, 512, 0, stream>>>(off_c, pos_c, ns1, off_w, pos_w, ns2,
                                   off_wr, pos_wr, ns3, bsum);
  }
  bucket3<<<256, 256, 0, stream>>>(c_dst, c_src, c_w, Ec, pos_c, srcs_c, wgts_c,
                                   w_dst, w_src, Ew, pos_w, srcs_w,
                                   wr_dst, wr_src, Ewr, pos_wr, srcs_wr);

  // ---- GEMMs: self -> d_out (f32), messages -> bf16 buffers ----
  dim3 gp((Mp + 127) / 128, 2), ga((Ma + 127) / 128, 2);
  gemm_bias<true><<<gp, 256, 0, stream>>>(x_p, WT_sp, b_sp, out_p, Mp);
  gemm_bias<true><<<ga, 256, 0, stream>>>(x_a, WT_sa, b_sa, out_a, Ma);
  gemm_bias<false><<<gp, 256, 0, stream>>>(x_p, WT_c,  b_c,  msg_c,  Mp);
  gemm_bias<false><<<ga, 256, 0, stream>>>(x_a, WT_w,  b_w,  msg_w,  Ma);
  gemm_bias<false><<<gp, 256, 0, stream>>>(x_p, WT_wr, b_wr, msg_wr, Mp);

  // ---- fused gather-accumulate + ELU (paper + author in one grid) ----
  int totalWaves = Mp + Ma;
  accum_fused<<<(totalWaves + 3) / 4, 256, 0, stream>>>(
      out_p, Mp, out_a, Ma,
      msg_c, off_c, srcs_c, wgts_c,
      msg_w, off_w, srcs_w,
      msg_wr, off_wr, srcs_wr);
}

// Round 6
// 490.170 us; speedup vs baseline: 5.4545x; 1.0221x over previous
//
#include <hip/hip_runtime.h>
#include <stdint.h>

typedef __attribute__((ext_vector_type(8))) short short8;
typedef __attribute__((ext_vector_type(4))) float f32x4;

__device__ __forceinline__ unsigned short f2b(float f) {
  union { float f; uint32_t u; } v; v.f = f;
  uint32_t r = (v.u + 0x7fffu + ((v.u >> 16) & 1u)) >> 16;
  return (unsigned short)r;
}
__device__ __forceinline__ float b2f(unsigned short h) {
  union { uint32_t u; float f; } v; v.u = ((uint32_t)h) << 16; return v.f;
}

__device__ __forceinline__ void load_lds16(const void* g, void* l) {
  __builtin_amdgcn_global_load_lds(
      (const __attribute__((address_space(1))) uint32_t*)g,
      (__attribute__((address_space(3))) uint32_t*)l, 16, 0, 0);
}

// ------------- 5x fused 256x256 transpose+cast (f32 W[k][n] -> bf16 WT[n][k]) -------------
__global__ void transpose_cast5(
    const float* __restrict__ W0, const float* __restrict__ W1,
    const float* __restrict__ W2, const float* __restrict__ W3,
    const float* __restrict__ W4,
    unsigned short* __restrict__ T0, unsigned short* __restrict__ T1,
    unsigned short* __restrict__ T2, unsigned short* __restrict__ T3,
    unsigned short* __restrict__ T4) {
  const float* W; unsigned short* T;
  switch (blockIdx.y) {
    case 0: W = W0; T = T0; break;
    case 1: W = W1; T = T1; break;
    case 2: W = W2; T = T2; break;
    case 3: W = W3; T = T3; break;
    default: W = W4; T = T4; break;
  }
  __shared__ unsigned short t[32][33];
  int bx = blockIdx.x & 7, by = blockIdx.x >> 3;
  int x = threadIdx.x & 31, y = threadIdx.x >> 5;  // 32x8
  for (int i = 0; i < 32; i += 8)
    t[y + i][x] = f2b(W[(by * 32 + y + i) * 256 + bx * 32 + x]);
  __syncthreads();
  for (int i = 0; i < 32; i += 8)
    T[(bx * 32 + y + i) * 256 + by * 32 + x] = t[x][y + i];
}

// ------------- multi-B GEMM: NMAT outputs sharing the A operand -------------
// A f32 [M,256] row-major, staged once per tile (f32->bf16, swizzled ds_write).
// Block tile: 128 rows x 64 cols; 4 waves (2x2), wave tile 64x32.
// mat 0 writes f32 to out0; mats 1,2 write bf16 to out1/out2.
template <int NMAT>
__global__ __launch_bounds__(256, 2) void gemm_multi(
    const float* __restrict__ A,
    const unsigned short* __restrict__ WT0, const unsigned short* __restrict__ WT1,
    const unsigned short* __restrict__ WT2,
    const float* __restrict__ b0, const float* __restrict__ b1,
    const float* __restrict__ b2,
    float* __restrict__ out0, unsigned short* __restrict__ out1,
    unsigned short* __restrict__ out2, int M) {
  __shared__ uint8_t lds[16384 + NMAT * 8192];
  uint8_t* ldsA = lds;

  const int tid = threadIdx.x;
  const int lane = tid & 63;
  const int w = tid >> 6;
  const int wr = w >> 1, wc = w & 1;
  const int row0 = blockIdx.x * 128;
  const int n0 = blockIdx.y * 64;

  f32x4 acc[NMAT][4][2] = {};

  for (int kt = 0; kt < 4; ++kt) {
    const int kk = kt << 6;
    // --- stage B tiles (64 cols x 64 k each) via global_load_lds ---
#pragma unroll
    for (int mat = 0; mat < NMAT; ++mat) {
      const unsigned short* WT = mat == 0 ? WT0 : (mat == 1 ? WT1 : WT2);
      uint8_t* ldsB = lds + 16384 + mat * 8192;
#pragma unroll
      for (int c = 0; c < 2; ++c) {
        int q = c * 256 + tid;            // 16B chunk index, 512 chunks
        int row = q >> 3, ch = q & 7;
        int lch = ch ^ (row & 7);
        load_lds16(WT + (size_t)(n0 + row) * 256 + kk + lch * 8, ldsB + q * 16);
      }
    }
    // --- stage A (128 rows x 64 k): f32 load -> bf16 -> swizzled ds_write ---
#pragma unroll
    for (int c = 0; c < 4; ++c) {
      int q = c * 256 + tid;
      int row = q >> 3, ch = q & 7;
      int ar = row0 + row;
      if (ar >= M) ar = M - 1;
      const float* ap = A + (size_t)ar * 256 + kk + ch * 8;
      float4 f0 = *(const float4*)(ap);
      float4 f1 = *(const float4*)(ap + 4);
      short8 s;
      s[0] = (short)f2b(f0.x); s[1] = (short)f2b(f0.y);
      s[2] = (short)f2b(f0.z); s[3] = (short)f2b(f0.w);
      s[4] = (short)f2b(f1.x); s[5] = (short)f2b(f1.y);
      s[6] = (short)f2b(f1.z); s[7] = (short)f2b(f1.w);
      *(short8*)(ldsA + row * 128 + ((ch ^ (row & 7)) << 4)) = s;
    }
    asm volatile("s_waitcnt vmcnt(0)" ::: "memory");
    __syncthreads();

#pragma unroll
    for (int s = 0; s < 2; ++s) {
      const int cbase = (s << 2) + (lane >> 4);
      short8 av[4];
#pragma unroll
      for (int m = 0; m < 4; ++m) {
        int r = wr * 64 + m * 16 + (lane & 15);
        av[m] = *(const short8*)(ldsA + r * 128 + ((cbase ^ (r & 7)) << 4));
      }
#pragma unroll
      for (int mat = 0; mat < NMAT; ++mat) {
        uint8_t* ldsB = lds + 16384 + mat * 8192;
        short8 bv[2];
#pragma unroll
        for (int n = 0; n < 2; ++n) {
          int cc = wc * 32 + n * 16 + (lane & 15);
          bv[n] = *(const short8*)(ldsB + cc * 128 + ((cbase ^ (cc & 7)) << 4));
        }
#pragma unroll
        for (int m = 0; m < 4; ++m)
#pragma unroll
          for (int n = 0; n < 2; ++n)
            acc[mat][m][n] = __builtin_amdgcn_mfma_f32_16x16x32_bf16(
                av[m], bv[n], acc[mat][m][n], 0, 0, 0);
      }
    }
    __syncthreads();
  }

  // epilogue
#pragma unroll
  for (int mat = 0; mat < NMAT; ++mat) {
    const float* bb = mat == 0 ? b0 : (mat == 1 ? b1 : b2);
#pragma unroll
    for (int n = 0; n < 2; ++n) {
      int col = n0 + wc * 32 + n * 16 + (lane & 15);
      float bval = bb[col];
#pragma unroll
      for (int m = 0; m < 4; ++m) {
#pragma unroll
        for (int j = 0; j < 4; ++j) {
          int row = row0 + wr * 64 + m * 16 + (lane >> 4) * 4 + j;
          if (row < M) {
            float v = acc[mat][m][n][j] + bval;
            if (mat == 0)
              out0[(size_t)row * 256 + col] = v;
            else if (mat == 1)
              out1[(size_t)row * 256 + col] = f2b(v);
            else
              out2[(size_t)row * 256 + col] = f2b(v);
          }
        }
      }
    }
  }
}

// ------------- CSR build (fused over 3 relations) -------------
__global__ void hist3(const int* __restrict__ d1, int E1, int* __restrict__ c1,
                      const int* __restrict__ d2, int E2, int* __restrict__ c2,
                      const int* __restrict__ d3, int E3, int* __restrict__ c3) {
  int i = blockIdx.x * blockDim.x + threadIdx.x;
  int stride = gridDim.x * blockDim.x;
  int tot = E1 + E2 + E3;
  for (; i < tot; i += stride) {
    if (i < E1) atomicAdd(&c1[d1[i]], 1);
    else if (i < E1 + E2) atomicAdd(&c2[d2[i - E1]], 1);
    else atomicAdd(&c3[d3[i - E1 - E2]], 1);
  }
}

__global__ void scan512_3(const int* __restrict__ c1, int* __restrict__ o1, int ns1,
                          const int* __restrict__ c2, int* __restrict__ o2, int ns2,
                          const int* __restrict__ c3, int* __restrict__ o3, int ns3,
                          int* __restrict__ bsum) {
  const int* in; int* out; int ns;
  switch (blockIdx.y) {
    case 0: in = c1; out = o1; ns = ns1; break;
    case 1: in = c2; out = o2; ns = ns2; break;
    default: in = c3; out = o3; ns = ns3; break;
  }
  if ((int)blockIdx.x * 512 >= ns) return;
  __shared__ int s[512];
  int t = threadIdx.x;
  int i = blockIdx.x * 512 + t;
  int v = (i < ns) ? in[i] : 0;
  s[t] = v;
  __syncthreads();
  for (int off = 1; off < 512; off <<= 1) {
    int x = s[t];
    int y = (t >= off) ? s[t - off] : 0;
    __syncthreads();
    s[t] = x + y;
    __syncthreads();
  }
  if (i < ns) out[i] = s[t] - v;  // exclusive
  if (t == 511) bsum[blockIdx.y * 512 + blockIdx.x] = s[511];
}

__global__ void scan_bsums3(int* __restrict__ bsum, int B1, int B2, int B3) {
  int rel = blockIdx.x;
  int B = rel == 0 ? B1 : (rel == 1 ? B2 : B3);
  int* bs = bsum + rel * 512;
  __shared__ int s[512];
  int t = threadIdx.x;
  int v = (t < B) ? bs[t] : 0;
  s[t] = v;
  __syncthreads();
  for (int off = 1; off < 512; off <<= 1) {
    int x = s[t];
    int y = (t >= off) ? s[t - off] : 0;
    __syncthreads();
    s[t] = x + y;
    __syncthreads();
  }
  if (t < B) bs[t] = s[t] - v;  // exclusive
}

__global__ void addoff3(int* __restrict__ o1, int* __restrict__ p1, int ns1,
                        int* __restrict__ o2, int* __restrict__ p2, int ns2,
                        int* __restrict__ o3, int* __restrict__ p3, int ns3,
                        const int* __restrict__ bsum) {
  int* o; int* p; int ns;
  switch (blockIdx.y) {
    case 0: o = o1; p = p1; ns = ns1; break;
    case 1: o = o2; p = p2; ns = ns2; break;
    default: o = o3; p = p3; ns = ns3; break;
  }
  int i = blockIdx.x * 512 + threadIdx.x;
  if (i < ns) {
    int v = o[i] + bsum[blockIdx.y * 512 + blockIdx.x];
    o[i] = v;
    p[i] = v;
  }
}

__global__ void bucket3(
    const int* __restrict__ d1, const int* __restrict__ s1in,
    const float* __restrict__ w1in, int E1, int* __restrict__ p1,
    int* __restrict__ s1, float* __restrict__ w1,
    const int* __restrict__ d2, const int* __restrict__ s2in, int E2,
    int* __restrict__ p2, int* __restrict__ s2,
    const int* __restrict__ d3, const int* __restrict__ s3in, int E3,
    int* __restrict__ p3, int* __restrict__ s3) {
  int i = blockIdx.x * blockDim.x + threadIdx.x;
  int stride = gridDim.x * blockDim.x;
  int tot = E1 + E2 + E3;
  for (; i < tot; i += stride) {
    if (i < E1) {
      int p = atomicAdd(&p1[d1[i]], 1);
      s1[p] = s1in[i];
      w1[p] = w1in[i];
    } else if (i < E1 + E2) {
      int k = i - E1;
      int p = atomicAdd(&p2[d2[k]], 1);
      s2[p] = s2in[k];
    } else {
      int k = i - E1 - E2;
      int p = atomicAdd(&p3[d3[k]], 1);
      s3[p] = s3in[k];
    }
  }
}

// ------------- fused gather-accumulate + ELU (2 waves per dst row) -------------
// Each wave owns 128 channels (ushort2 per lane); chan = half*128 + lane*2.
template <bool WEIGHTED>
__device__ __forceinline__ void gather_acc(float& v0, float& v1,
                                           const unsigned short* __restrict__ msg,
                                           const int* __restrict__ srcs,
                                           const float* __restrict__ wgts,
                                           int b, int e, int chan) {
  int j = b;
  for (; j + 4 <= e; j += 4) {
    int sa = srcs[j], sb = srcs[j + 1], sc = srcs[j + 2], sd = srcs[j + 3];
    float wa = 1.f, wb = 1.f, wc = 1.f, wd = 1.f;
    if (WEIGHTED) { wa = wgts[j]; wb = wgts[j + 1]; wc = wgts[j + 2]; wd = wgts[j + 3]; }
    ushort2 ma = *(const ushort2*)(msg + ((size_t)sa << 8) + chan);
    ushort2 mb = *(const ushort2*)(msg + ((size_t)sb << 8) + chan);
    ushort2 mc = *(const ushort2*)(msg + ((size_t)sc << 8) + chan);
    ushort2 md = *(const ushort2*)(msg + ((size_t)sd << 8) + chan);
    v0 += wa * b2f(ma.x) + wb * b2f(mb.x) + wc * b2f(mc.x) + wd * b2f(md.x);
    v1 += wa * b2f(ma.y) + wb * b2f(mb.y) + wc * b2f(mc.y) + wd * b2f(md.y);
  }
  if (j + 2 <= e) {
    int sa = srcs[j], sb = srcs[j + 1];
    float wa = 1.f, wb = 1.f;
    if (WEIGHTED) { wa = wgts[j]; wb = wgts[j + 1]; }
    ushort2 ma = *(const ushort2*)(msg + ((size_t)sa << 8) + chan);
    ushort2 mb = *(const ushort2*)(msg + ((size_t)sb << 8) + chan);
    v0 += wa * b2f(ma.x) + wb * b2f(mb.x);
    v1 += wa * b2f(ma.y) + wb * b2f(mb.y);
    j += 2;
  }
  if (j < e) {
    int s = srcs[j];
    float w = WEIGHTED ? wgts[j] : 1.f;
    ushort2 m = *(const ushort2*)(msg + ((size_t)s << 8) + chan);
    v0 += w * b2f(m.x);
    v1 += w * b2f(m.y);
  }
}

__global__ void accum_fused(
    float* __restrict__ io_p, int Np, float* __restrict__ io_a, int Na,
    const unsigned short* __restrict__ msg1, const int* __restrict__ off1,
    const int* __restrict__ s1, const float* __restrict__ w1,
    const unsigned short* __restrict__ msg2, const int* __restrict__ off2,
    const int* __restrict__ s2,
    const unsigned short* __restrict__ msg3, const int* __restrict__ off3,
    const int* __restrict__ s3) {
  int gw = (blockIdx.x * blockDim.x + threadIdx.x) >> 6;
  int lane = threadIdx.x & 63;
  int row = gw >> 1;
  int chan = (gw & 1) * 128 + lane * 2;   // channel offset within the 256-wide row
  float* rp;
  float v0, v1;
  if (row < Np) {
    rp = io_p + (size_t)row * 256 + chan;
    float2 v = *(float2*)rp;
    v0 = v.x; v1 = v.y;
    gather_acc<true>(v0, v1, msg1, s1, w1, off1[row], off1[row + 1], chan);
    gather_acc<false>(v0, v1, msg2, s2, nullptr, off2[row], off2[row + 1], chan);
  } else if (row < Np + Na) {
    int r = row - Np;
    rp = io_a + (size_t)r * 256 + chan;
    float2 v = *(float2*)rp;
    v0 = v.x; v1 = v.y;
    gather_acc<false>(v0, v1, msg3, s3, nullptr, off3[r], off3[r + 1], chan);
  } else {
    return;
  }
  float2 o;
  o.x = v0 > 0.f ? v0 : expf(v0) - 1.f;
  o.y = v1 > 0.f ? v1 : expf(v1) - 1.f;
  *(float2*)rp = o;
}

extern "C" void kernel_launch(void* const* d_in, const int* in_sizes, int n_in,
                              void* d_out, int out_size, void* d_ws, size_t ws_size,
                              hipStream_t stream) {
  const float* x_p = (const float*)d_in[0];
  const float* x_a = (const float*)d_in[1];
  const int* c_src = (const int*)d_in[2];
  const int* c_dst = (const int*)d_in[3];
  const float* c_w = (const float*)d_in[4];
  const int* w_src = (const int*)d_in[5];
  const int* w_dst = (const int*)d_in[6];
  const int* wr_src = (const int*)d_in[7];
  const int* wr_dst = (const int*)d_in[8];
  const float* W_sp = (const float*)d_in[9];
  const float* b_sp = (const float*)d_in[10];
  const float* W_sa = (const float*)d_in[11];
  const float* b_sa = (const float*)d_in[12];
  const float* W_c  = (const float*)d_in[13];
  const float* b_c  = (const float*)d_in[14];
  const float* W_w  = (const float*)d_in[15];
  const float* b_w  = (const float*)d_in[16];
  const float* W_wr = (const float*)d_in[17];
  const float* b_wr = (const float*)d_in[18];

  const int Mp = in_sizes[0] / 256;
  const int Ma = in_sizes[1] / 256;
  const int Ec = in_sizes[2], Ew = in_sizes[5], Ewr = in_sizes[7];

  // ---- workspace bump allocator (256B aligned) ----
  size_t wo = 0;
  auto alloc = [&](size_t bytes) -> void* {
    void* p = (char*)d_ws + wo;
    wo += (bytes + 255) & ~(size_t)255;
    return p;
  };
  unsigned short* msg_c  = (unsigned short*)alloc((size_t)Mp * 512);
  unsigned short* msg_w  = (unsigned short*)alloc((size_t)Ma * 512);
  unsigned short* msg_wr = (unsigned short*)alloc((size_t)Mp * 512);
  unsigned short* WT_sp = (unsigned short*)alloc(131072);
  unsigned short* WT_sa = (unsigned short*)alloc(131072);
  unsigned short* WT_c  = (unsigned short*)alloc(131072);
  unsigned short* WT_w  = (unsigned short*)alloc(131072);
  unsigned short* WT_wr = (unsigned short*)alloc(131072);
  int* cnt_c  = (int*)alloc((size_t)((Mp + 1) + (Mp + 1) + (Ma + 1)) * 4);
  int* cnt_w  = cnt_c + (Mp + 1);
  int* cnt_wr = cnt_w + (Mp + 1);
  size_t cnt_bytes = (size_t)((Mp + 1) + (Mp + 1) + (Ma + 1)) * 4;
  int* off_c  = (int*)alloc((size_t)(Mp + 1) * 4);
  int* pos_c  = (int*)alloc((size_t)(Mp + 1) * 4);
  int* off_w  = (int*)alloc((size_t)(Mp + 1) * 4);
  int* pos_w  = (int*)alloc((size_t)(Mp + 1) * 4);
  int* off_wr = (int*)alloc((size_t)(Ma + 1) * 4);
  int* pos_wr = (int*)alloc((size_t)(Ma + 1) * 4);
  int* srcs_c  = (int*)alloc((size_t)Ec * 4);
  float* wgts_c = (float*)alloc((size_t)Ec * 4);
  int* srcs_w  = (int*)alloc((size_t)Ew * 4);
  int* srcs_wr = (int*)alloc((size_t)Ewr * 4);
  int* bsum = (int*)alloc(3 * 512 * 4);

  float* out_p = (float*)d_out;
  float* out_a = (float*)d_out + (size_t)Mp * 256;

  // ---- weight transposes (1 dispatch) ----
  {
    dim3 g(64, 5);
    transpose_cast5<<<g, 256, 0, stream>>>(W_sp, W_sa, W_c, W_w, W_wr,
                                           WT_sp, WT_sa, WT_c, WT_w, WT_wr);
  }

  // ---- CSR build (6 dispatches) ----
  const int ns1 = Mp + 1, ns2 = Mp + 1, ns3 = Ma + 1;
  const int B1 = (ns1 + 511) / 512, B2 = (ns2 + 511) / 512, B3 = (ns3 + 511) / 512;
  const int Bmax = B1 > B2 ? (B1 > B3 ? B1 : B3) : (B2 > B3 ? B2 : B3);
  hipMemsetAsync(cnt_c, 0, cnt_bytes, stream);
  hist3<<<256, 256, 0, stream>>>(c_dst, Ec, cnt_c, w_dst, Ew, cnt_w, wr_dst, Ewr, cnt_wr);
  {
    dim3 g(Bmax, 3);
    scan512_3<<<g, 512, 0, stream>>>(cnt_c, off_c, ns1, cnt_w, off_w, ns2,
                                     cnt_wr, off_wr, ns3, bsum);
    scan_bsums3<<<3, 512, 0, stream>>>(bsum, B1, B2, B3);
    addoff3<<<g, 512, 0, stream>>>(off_c, pos_c, ns1, off_w, pos_w, ns2,
                                   off_wr, pos_wr, ns3, bsum);
  }
  bucket3<<<256, 256, 0, stream>>>(c_dst, c_src, c_w, Ec, pos_c, srcs_c, wgts_c,
                                   w_dst, w_src, Ew, pos_w, srcs_w,
                                   wr_dst, wr_src, Ewr, pos_wr, srcs_wr);

  // ---- fused GEMMs: paper (self+cites+written), author (self+writes) ----
  {
    dim3 gp((Mp + 127) / 128, 4);
    gemm_multi<3><<<gp, 256, 0, stream>>>(x_p, WT_sp, WT_c, WT_wr,
                                          b_sp, b_c, b_wr,
                                          out_p, msg_c, msg_wr, Mp);
    dim3 ga((Ma + 127) / 128, 4);
    gemm_multi<2><<<ga, 256, 0, stream>>>(x_a, WT_sa, WT_w, nullptr,
                                          b_sa, b_w, nullptr,
                                          out_a, msg_w, nullptr, Ma);
  }

  // ---- fused gather-accumulate + ELU (2 waves per row) ----
  int totalWaves = 2 * (Mp + Ma);
  accum_fused<<<(totalWaves + 3) / 4, 256, 0, stream>>>(
      out_p, Mp, out_a, Ma,
      msg_c, off_c, srcs_c, wgts_c,
      msg_w, off_w, srcs_w,
      msg_wr, off_wr, srcs_wr);
}